// Round 1
// baseline (479.859 us; speedup 1.0000x reference)
//
#include <hip/hip_runtime.h>

constexpr int kB  = 32;
constexpr int kNQ = 256;   // rows n
constexpr int kNT = 512;   // cols m
constexpr float kInf = 1e30f;
constexpr int kQTile = 8;     // queries per cost block (was 32; grid 256->1024 for occupancy)
constexpr int kSlots = 64;    // direct-mapped LDS row-cache entries (slot = row & 63)
constexpr int kStride = 544;  // 8 groups x (64 data + 4 pad) floats

// ---------------------------------------------------------------------------
// Kernel 1: final_cost [B, NQ, NT]. 512 thr/block, thread == target t.
// Math per output element bit-identical to the proven kernel; only the
// q-tiling changed (32 -> 8) to raise blocks/CU from 1 to 3 (LDS-capped).
// ---------------------------------------------------------------------------
__global__ __launch_bounds__(512)
void cost_kernel(const float* __restrict__ trans,
                 const float* __restrict__ qpos,
                 const float* __restrict__ rot,
                 const float* __restrict__ pose,
                 float* __restrict__ cost)
{
    __shared__ float sPose[kNT * 23];   // 47104 B -> 3 blocks/CU

    const int b     = blockIdx.x;
    const int qBase = blockIdx.y * kQTile;
    const int tid   = threadIdx.x;      // target index t

    const float* pb = pose + (size_t)b * kNT * 23;
    for (int idx = tid; idx < kNT * 23; idx += 512) sPose[idx] = pb[idx];
    __syncthreads();

    float T[23];
    #pragma unroll
    for (int d = 0; d < 23; ++d) T[d] = sPose[tid * 23 + d];

    float s = 0.f;
    #pragma unroll
    for (int d = 0; d < 23; ++d) s += fabsf(T[d]);
    const bool valid = (s > 0.f);

    const float* tr = trans + ((size_t)b * kNQ + qBase) * 3;
    const float* qp = qpos  + ((size_t)b * kNQ + qBase) * 16;
    const float* rt = rot   + ((size_t)b * kNQ + qBase) * 4;
    float* cb = cost + ((size_t)b * kNQ + qBase) * kNT + tid;

    #pragma unroll
    for (int q = 0; q < kQTile; ++q) {
        const float Q0 = tr[q * 3 + 0], Q1 = tr[q * 3 + 1], Q2 = tr[q * 3 + 2];
        float a = fabsf(Q0 - T[0]);
        a += fabsf(Q1 - T[1]);
        a += fabsf(Q2 - T[2]);
        float bsum = 0.f;
        #pragma unroll
        for (int d = 0; d < 16; ++d) bsum += fabsf(qp[q * 16 + d] - T[3 + d]);
        const float r0 = rt[q * 4 + 0], r1 = rt[q * 4 + 1];
        const float r2 = rt[q * 4 + 2], r3 = rt[q * 4 + 3];
        float dot = r0 * T[19] + r1 * T[20] + r2 * T[21] + r3 * T[22];
        float c = (a + bsum) + (1.0f - fabsf(dot));
        cb[(size_t)q * kNT] = valid ? c : kInf;
    }
}

// Wave64 min-reduction via DPP (rocPRIM pattern). All inputs are non-negative
// float bit-patterns (incl +inf sentinel), so u32 order == f32 order.
__device__ __forceinline__ unsigned wave_min_u32(unsigned x) {
    unsigned t;
    t = (unsigned)__builtin_amdgcn_update_dpp((int)0xFFFFFFFF, (int)x, 0x111, 0xF, 0xF, false); x = t < x ? t : x; // row_shr:1
    t = (unsigned)__builtin_amdgcn_update_dpp((int)0xFFFFFFFF, (int)x, 0x112, 0xF, 0xF, false); x = t < x ? t : x; // row_shr:2
    t = (unsigned)__builtin_amdgcn_update_dpp((int)0xFFFFFFFF, (int)x, 0x114, 0xF, 0xF, false); x = t < x ? t : x; // row_shr:4
    t = (unsigned)__builtin_amdgcn_update_dpp((int)0xFFFFFFFF, (int)x, 0x118, 0xF, 0xF, false); x = t < x ? t : x; // row_shr:8
    t = (unsigned)__builtin_amdgcn_update_dpp((int)0xFFFFFFFF, (int)x, 0x142, 0xF, 0xF, false); x = t < x ? t : x; // row_bcast:15
    t = (unsigned)__builtin_amdgcn_update_dpp((int)0xFFFFFFFF, (int)x, 0x143, 0xF, 0xF, false); x = t < x ? t : x; // row_bcast:31
    return (unsigned)__builtin_amdgcn_readlane((int)x, 63);
}

// ---------------------------------------------------------------------------
// Kernel 2: JV LSAP — numerics and selection order frozen (bit-identical to
// the passing kernel). This round changes only DATA MOVEMENT latency:
//   - direct-mapped row cache (slot = i & 63): ds_read address known ~15cy
//     after i; tag check via readlane(tagReg, slot) runs parallel to the
//     load. Removes the ballot+ffs cache lookup (~30cy) from the load path.
//   - col4row / row4col / path live in lane-distributed REGISTERS; augment
//     walk = cndmask-select + readlane per hop (~50cy) instead of dependent
//     LDS reads (~480cy). Matched-row skip likewise register-resident.
//   - frzO records the swept column's owner at freeze time (== the spec
//     prefetch value), so dual updates need no row4col re-read; u[r] RMWs
//     are gathered (all reads, then all writes; owners provably distinct).
// ---------------------------------------------------------------------------
__global__ __launch_bounds__(256)
void hungarian_kernel(const float* __restrict__ cost,
                      float* __restrict__ outInds,
                      float* __restrict__ outMask)
{
    __shared__ float rowCache[kSlots * kStride];  // 139264 B
    __shared__ float u[kNQ];
    __shared__ int   col4row[kNQ];
    __shared__ int   row4col[kNT];
    __shared__ int   colBest[kNT];
    __shared__ int   rowArg[kNQ];

    const int b   = blockIdx.x;
    const int tid = threadIdx.x;
    const float* __restrict__ C = cost + (size_t)b * kNQ * kNT;

    // ---- Phase A: row minima + greedy matching (thread t == row t) ----
    {
        const float4* Crow = (const float4*)(C + (size_t)tid * kNT);
        float bm = kInf; int barg = 0;
        #pragma unroll 4
        for (int j4 = 0; j4 < kNT / 4; ++j4) {
            float4 cc = Crow[j4];
            const int jb = j4 * 4;
            if (cc.x < bm) { bm = cc.x; barg = jb + 0; }
            if (cc.y < bm) { bm = cc.y; barg = jb + 1; }
            if (cc.z < bm) { bm = cc.z; barg = jb + 2; }
            if (cc.w < bm) { bm = cc.w; barg = jb + 3; }
        }
        u[tid]      = bm;   // feasible: C - u - 0 >= 0 exactly; matched slack == 0 exactly
        rowArg[tid] = barg;
        col4row[tid] = -1;
    }
    row4col[tid] = -1;         row4col[tid + 256] = -1;
    colBest[tid] = 0x7fffffff; colBest[tid + 256] = 0x7fffffff;
    __syncthreads();
    atomicMin(&colBest[rowArg[tid]], tid);
    __syncthreads();
    {
        const int j = rowArg[tid];
        if (colBest[j] == tid) { col4row[tid] = j; row4col[j] = tid; }
    }
    __syncthreads();

    // ---- Phase C: augmenting searches, wave 0 only (wave-synchronous) ----
    if (tid < 64) {
        const int lane = tid;
        const int laneOff = (lane >> 3) * 68 + (lane & 7) * 8;
        typedef float v2f __attribute__((ext_vector_type(2)));

        float vR[8];
        #pragma unroll
        for (int c = 0; c < 8; ++c) vR[c] = 0.f;

        // matching state in registers: lane l holds col4row[l*4+e] (e=0..3)
        // and row4col[l*8+e] (e=0..7)
        int c4r0 = col4row[lane * 4 + 0], c4r1 = col4row[lane * 4 + 1];
        int c4r2 = col4row[lane * 4 + 2], c4r3 = col4row[lane * 4 + 3];
        int r4c0 = row4col[lane * 8 + 0], r4c1 = row4col[lane * 8 + 1];
        int r4c2 = row4col[lane * 8 + 2], r4c3 = row4col[lane * 8 + 3];
        int r4c4 = row4col[lane * 8 + 4], r4c5 = row4col[lane * 8 + 5];
        int r4c6 = row4col[lane * 8 + 6], r4c7 = row4col[lane * 8 + 7];

        int tagReg = -1;   // row cached in slot 'lane' (direct-mapped)

        for (int cur = 0; cur < kNQ; ++cur) {
            // matched-row skip from registers (~30cy vs ~140cy LDS)
            {
                const int ce = cur & 3;
                const int t01 = (ce & 1) ? c4r1 : c4r0;
                const int t23 = (ce & 1) ? c4r3 : c4r2;
                const int cv  = (ce & 2) ? t23 : t01;
                if (__builtin_amdgcn_readlane(cv, cur >> 2) >= 0) continue;
            }

            float spcR[8]; int pathR[8]; float mskA[8]; float frzV[8]; int frzP[8]; int frzO[8];
            #pragma unroll
            for (int c = 0; c < 8; ++c) {
                spcR[c] = kInf; pathR[c] = -1; mskA[c] = 0.f;
                frzV[c] = 0.f;  frzP[c] = -1;  frzO[c] = -1;
            }
            unsigned scMask = 0;

            int   i      = cur;
            float minVal = 0.f;
            int   sink   = -1;

            for (int guard = 0; guard < kNT + 2 && sink < 0; ++guard) {
                // ---- direct-mapped cache: issue ds_read immediately; tag
                //      check (readlane, slot uniform) overlaps the load ----
                const int slot = i & (kSlots - 1);
                float* lrow = &rowCache[slot * kStride + laneOff];
                const float4 l0 = ((const float4*)lrow)[0];
                const float4 l1 = ((const float4*)lrow)[1];
                const float ui = u[i];            // LDS read, overlaps row fetch
                const int tag = __builtin_amdgcn_readlane(tagReg, slot);

                float4 p0, p1;
                if (tag == i) {                   // hit (wave-uniform branch)
                    p0 = l0; p1 = l1;
                } else {                          // miss: global (L2) load + fill
                    const float4* gp = (const float4*)(C + (size_t)i * kNT + lane * 8);
                    p0 = gp[0]; p1 = gp[1];
                    ((float4*)lrow)[0] = p0; ((float4*)lrow)[1] = p1;
                    if (lane == slot) tagReg = i;
                }

                // ---- UNMASKED packed relax (value-exact op order) ----
                const v2f cc2[4] = { {p0.x, p0.y}, {p0.z, p0.w},
                                     {p1.x, p1.y}, {p1.z, p1.w} };
                const v2f mv2 = { minVal, minVal };
                const v2f ui2 = { ui, ui };
                float r8[8];
                #pragma unroll
                for (int p = 0; p < 4; ++p) {
                    const v2f vv = { vR[2*p], vR[2*p + 1] };
                    const v2f rp2 = ((mv2 + cc2[p]) - ui2) - vv;
                    r8[2*p] = rp2.x; r8[2*p + 1] = rp2.y;
                }
                #pragma unroll
                for (int c = 0; c < 8; ++c) {
                    const bool lt = r8[c] < spcR[c];
                    spcR[c]  = lt ? r8[c] : spcR[c];
                    pathR[c] = lt ? i : pathR[c];
                }

                // ---- masked local argmin: msk = spc + {0|+inf}, u32 tree ----
                float mskv[8];
                #pragma unroll
                for (int p = 0; p < 4; ++p) {
                    const v2f s2 = { spcR[2*p], spcR[2*p + 1] };
                    const v2f a2 = { mskA[2*p], mskA[2*p + 1] };
                    const v2f m2 = s2 + a2;
                    mskv[2*p] = m2.x; mskv[2*p + 1] = m2.y;
                }
                unsigned sp[8];
                #pragma unroll
                for (int c = 0; c < 8; ++c) sp[c] = __float_as_uint(mskv[c]);
                unsigned mA = sp[1] < sp[0] ? sp[1] : sp[0]; int aA = sp[1] < sp[0] ? 1 : 0;
                unsigned mB = sp[3] < sp[2] ? sp[3] : sp[2]; int aB = sp[3] < sp[2] ? 3 : 2;
                unsigned mC = sp[5] < sp[4] ? sp[5] : sp[4]; int aC = sp[5] < sp[4] ? 5 : 4;
                unsigned mD = sp[7] < sp[6] ? sp[7] : sp[6]; int aD = sp[7] < sp[6] ? 7 : 6;
                unsigned mAB = mB < mA ? mB : mA; int aAB = mB < mA ? aB : aA;
                unsigned mCD = mD < mC ? mD : mC; int aCD = mD < mC ? aD : aC;
                unsigned lvu = mCD < mAB ? mCD : mAB; int lc = mCD < mAB ? aCD : aAB;
                const int lix  = lane * 8 + lc;

                // speculative owner prefetch from REGISTERS (3-level select)
                const int s01 = (lc & 1) ? r4c1 : r4c0;
                const int s23 = (lc & 1) ? r4c3 : r4c2;
                const int s45 = (lc & 1) ? r4c5 : r4c4;
                const int s67 = (lc & 1) ? r4c7 : r4c6;
                const int sAq = (lc & 2) ? s23 : s01;
                const int sBq = (lc & 2) ? s67 : s45;
                const int spec = (lc & 4) ? sBq : sAq;

                const unsigned gmu = wave_min_u32(lvu);
                const unsigned long long bal = __ballot(lvu == gmu);
                const int wl    = (int)__ffsll(bal) - 1;
                const int jstar = __builtin_amdgcn_readlane(lix, wl);
                const int own   = __builtin_amdgcn_readlane(spec, wl);
                minVal = __uint_as_float(gmu);

                if (own < 0) sink = jstar;
                else         i    = own;

                if (wl == lane) {                 // freeze sweep-time state
                    const int lcw = jstar & 7;
                    scMask |= 1u << lcw;
                    #pragma unroll
                    for (int c = 0; c < 8; ++c) {
                        if (c == lcw) {
                            mskA[c] = __builtin_inff();
                            frzV[c] = minVal;     // == spcR[c] at sweep time
                            frzP[c] = pathR[c];
                            frzO[c] = spec;       // == row4col[jstar] at sweep time
                        }
                    }
                }
            }

            // ---- dual updates (sweep-time values; gathered u reads then
            //      writes — owners distinct by matching invariant) ----
            if (lane == 0) u[cur] += minVal;
            int   rr8[8]; float uv8[8];
            #pragma unroll
            for (int c = 0; c < 8; ++c) rr8[c] = ((scMask >> c) & 1u) ? frzO[c] : -1;
            #pragma unroll
            for (int c = 0; c < 8; ++c) uv8[c] = (rr8[c] >= 0) ? u[rr8[c]] : 0.f;
            #pragma unroll
            for (int c = 0; c < 8; ++c)
                if (rr8[c] >= 0) u[rr8[c]] = uv8[c] + (minVal - frzV[c]);
            #pragma unroll
            for (int c = 0; c < 8; ++c)
                if ((scMask >> c) & 1u) vR[c] -= (minVal - frzV[c]);
            __threadfence_block();

            // ---- augment along alternating path (register-resident;
            //      all lanes execute the uniform walk, ~50cy/hop) ----
            if (sink >= 0) {
                int j = sink;
                while (true) {
                    const int je = j & 7;
                    const int q01 = (je & 1) ? frzP[1] : frzP[0];
                    const int q23 = (je & 1) ? frzP[3] : frzP[2];
                    const int q45 = (je & 1) ? frzP[5] : frzP[4];
                    const int q67 = (je & 1) ? frzP[7] : frzP[6];
                    const int qA  = (je & 2) ? q23 : q01;
                    const int qB  = (je & 2) ? q67 : q45;
                    const int qv  = (je & 4) ? qB : qA;
                    const int pi  = __builtin_amdgcn_readlane(qv, j >> 3);

                    if (lane == (j >> 3)) {       // row4col[j] = pi
                        if (je == 0) r4c0 = pi; if (je == 1) r4c1 = pi;
                        if (je == 2) r4c2 = pi; if (je == 3) r4c3 = pi;
                        if (je == 4) r4c4 = pi; if (je == 5) r4c5 = pi;
                        if (je == 6) r4c6 = pi; if (je == 7) r4c7 = pi;
                    }

                    const int pe  = pi & 3;       // nj = col4row[pi]; col4row[pi] = j
                    const int w01 = (pe & 1) ? c4r1 : c4r0;
                    const int w23 = (pe & 1) ? c4r3 : c4r2;
                    const int wv  = (pe & 2) ? w23 : w01;
                    const int nj  = __builtin_amdgcn_readlane(wv, pi >> 2);
                    if (lane == (pi >> 2)) {
                        if (pe == 0) c4r0 = j; if (pe == 1) c4r1 = j;
                        if (pe == 2) c4r2 = j; if (pe == 3) c4r3 = j;
                    }

                    if (pi == cur) break;
                    j = nj;
                }
            }
        }

        // write matching back to LDS for the output phase
        col4row[lane * 4 + 0] = c4r0; col4row[lane * 4 + 1] = c4r1;
        col4row[lane * 4 + 2] = c4r2; col4row[lane * 4 + 3] = c4r3;
    }
    __syncthreads();

    outInds[(size_t)b * kNQ + tid] = (float)col4row[tid];
    outMask[(size_t)b * kNQ + tid] = 1.0f;
}

extern "C" void kernel_launch(void* const* d_in, const int* in_sizes, int n_in,
                              void* d_out, int out_size, void* d_ws, size_t ws_size,
                              hipStream_t stream) {
    const float* trans = (const float*)d_in[0];
    const float* qpos  = (const float*)d_in[1];
    const float* rot   = (const float*)d_in[2];
    const float* pose  = (const float*)d_in[3];

    float* out  = (float*)d_out;
    float* cost = out;
    float* inds = out + (size_t)kB * kNQ * kNT;
    float* mask = inds + (size_t)kB * kNQ;

    dim3 g1(kB, kNQ / kQTile);
    cost_kernel<<<g1, 512, 0, stream>>>(trans, qpos, rot, pose, cost);
    hungarian_kernel<<<kB, 256, 0, stream>>>(cost, inds, mask);
}

// Round 5
// 478.626 us; speedup vs baseline: 1.0026x; 1.0026x over previous
//
#include <hip/hip_runtime.h>

constexpr int kB  = 32;
constexpr int kNQ = 256;   // rows n
constexpr int kNT = 512;   // cols m
constexpr float kInf = 1e30f;
constexpr int kQTile = 8;     // queries per cost block (grid 1024; measured neutral-positive)
constexpr int kSlots = 56;    // LDS row-cache entries (R0 associative scheme, proven)
constexpr int kStride = 544;  // 8 groups x (64 data + 4 pad) floats

// ---------------------------------------------------------------------------
// Kernel 1: final_cost [B, NQ, NT]. 512 thr/block, thread == target t.
// Math per output element bit-identical to the proven kernel.
// ---------------------------------------------------------------------------
__global__ __launch_bounds__(512)
void cost_kernel(const float* __restrict__ trans,
                 const float* __restrict__ qpos,
                 const float* __restrict__ rot,
                 const float* __restrict__ pose,
                 float* __restrict__ cost)
{
    __shared__ float sPose[kNT * 23];   // 47104 B -> 3 blocks/CU

    const int b     = blockIdx.x;
    const int qBase = blockIdx.y * kQTile;
    const int tid   = threadIdx.x;      // target index t

    const float* pb = pose + (size_t)b * kNT * 23;
    for (int idx = tid; idx < kNT * 23; idx += 512) sPose[idx] = pb[idx];
    __syncthreads();

    float T[23];
    #pragma unroll
    for (int d = 0; d < 23; ++d) T[d] = sPose[tid * 23 + d];

    float s = 0.f;
    #pragma unroll
    for (int d = 0; d < 23; ++d) s += fabsf(T[d]);
    const bool valid = (s > 0.f);

    const float* tr = trans + ((size_t)b * kNQ + qBase) * 3;
    const float* qp = qpos  + ((size_t)b * kNQ + qBase) * 16;
    const float* rt = rot   + ((size_t)b * kNQ + qBase) * 4;
    float* cb = cost + ((size_t)b * kNQ + qBase) * kNT + tid;

    #pragma unroll
    for (int q = 0; q < kQTile; ++q) {
        const float Q0 = tr[q * 3 + 0], Q1 = tr[q * 3 + 1], Q2 = tr[q * 3 + 2];
        float a = fabsf(Q0 - T[0]);
        a += fabsf(Q1 - T[1]);
        a += fabsf(Q2 - T[2]);
        float bsum = 0.f;
        #pragma unroll
        for (int d = 0; d < 16; ++d) bsum += fabsf(qp[q * 16 + d] - T[3 + d]);
        const float r0 = rt[q * 4 + 0], r1 = rt[q * 4 + 1];
        const float r2 = rt[q * 4 + 2], r3 = rt[q * 4 + 3];
        float dot = r0 * T[19] + r1 * T[20] + r2 * T[21] + r3 * T[22];
        float c = (a + bsum) + (1.0f - fabsf(dot));
        cb[(size_t)q * kNT] = valid ? c : kInf;
    }
}

// Wave64 min-reduction via DPP (rocPRIM pattern). All inputs are non-negative
// float bit-patterns (incl +inf sentinel), so u32 order == f32 order.
__device__ __forceinline__ unsigned wave_min_u32(unsigned x) {
    unsigned t;
    t = (unsigned)__builtin_amdgcn_update_dpp((int)0xFFFFFFFF, (int)x, 0x111, 0xF, 0xF, false); x = t < x ? t : x; // row_shr:1
    t = (unsigned)__builtin_amdgcn_update_dpp((int)0xFFFFFFFF, (int)x, 0x112, 0xF, 0xF, false); x = t < x ? t : x; // row_shr:2
    t = (unsigned)__builtin_amdgcn_update_dpp((int)0xFFFFFFFF, (int)x, 0x114, 0xF, 0xF, false); x = t < x ? t : x; // row_shr:4
    t = (unsigned)__builtin_amdgcn_update_dpp((int)0xFFFFFFFF, (int)x, 0x118, 0xF, 0xF, false); x = t < x ? t : x; // row_shr:8
    t = (unsigned)__builtin_amdgcn_update_dpp((int)0xFFFFFFFF, (int)x, 0x142, 0xF, 0xF, false); x = t < x ? t : x; // row_bcast:15
    t = (unsigned)__builtin_amdgcn_update_dpp((int)0xFFFFFFFF, (int)x, 0x143, 0xF, 0xF, false); x = t < x ? t : x; // row_bcast:31
    return (unsigned)__builtin_amdgcn_readlane((int)x, 63);
}

// ---------------------------------------------------------------------------
// Kernel 2: JV LSAP. Sweep-loop load path is R0's EXACT ballot-associative
// 56-slot cache (direct-mapped variant regressed +40cy/iter in R1 —
// conflict-evictions + one-shot-row pollution; reverted). Changes vs R0, all
// OFF the per-iteration critical path and value-exact:
//   - col4row / row4col live in lane-distributed REGISTERS during Phase C;
//     matched-row skip, speculative owner prefetch, and the augment walk use
//     mux+readlane instead of dependent LDS reads (~60cy/hop vs ~450cy).
//   - frzO records the swept column's owner at freeze time (== sweep-time
//     row4col[jstar]; row4col is immutable during a search) so dual updates
//     need no LDS re-read.
//   - dual u[r] updates gathered: all reads, then all writes (owners are
//     distinct by the matching invariant; removes 8 dependent LDS RMWs).
// ---------------------------------------------------------------------------
__global__ __launch_bounds__(256)
void hungarian_kernel(const float* __restrict__ cost,
                      float* __restrict__ outInds,
                      float* __restrict__ outMask)
{
    __shared__ float rowCache[kSlots * kStride];  // 121856 B
    __shared__ float u[kNQ];
    __shared__ int   col4row[kNQ];
    __shared__ int   row4col[kNT];
    __shared__ int   colBest[kNT];
    __shared__ int   rowArg[kNQ];

    const int b   = blockIdx.x;
    const int tid = threadIdx.x;
    const float* __restrict__ C = cost + (size_t)b * kNQ * kNT;

    // ---- Phase A: row minima + greedy matching (thread t == row t) ----
    {
        const float4* Crow = (const float4*)(C + (size_t)tid * kNT);
        float bm = kInf; int barg = 0;
        #pragma unroll 4
        for (int j4 = 0; j4 < kNT / 4; ++j4) {
            float4 cc = Crow[j4];
            const int jb = j4 * 4;
            if (cc.x < bm) { bm = cc.x; barg = jb + 0; }
            if (cc.y < bm) { bm = cc.y; barg = jb + 1; }
            if (cc.z < bm) { bm = cc.z; barg = jb + 2; }
            if (cc.w < bm) { bm = cc.w; barg = jb + 3; }
        }
        u[tid]      = bm;   // feasible: C - u - 0 >= 0 exactly; matched slack == 0 exactly
        rowArg[tid] = barg;
        col4row[tid] = -1;
    }
    row4col[tid] = -1;         row4col[tid + 256] = -1;
    colBest[tid] = 0x7fffffff; colBest[tid + 256] = 0x7fffffff;
    __syncthreads();
    atomicMin(&colBest[rowArg[tid]], tid);
    __syncthreads();
    {
        const int j = rowArg[tid];
        if (colBest[j] == tid) { col4row[tid] = j; row4col[j] = tid; }
    }
    __syncthreads();

    // ---- Phase C: augmenting searches, wave 0 only (wave-synchronous) ----
    if (tid < 64) {
        const int lane = tid;
        const int laneOff = (lane >> 3) * 68 + (lane & 7) * 8;
        typedef float v2f __attribute__((ext_vector_type(2)));

        float vR[8];
        #pragma unroll
        for (int c = 0; c < 8; ++c) vR[c] = 0.f;

        // matching state in registers: lane l holds col4row[l*4+e] (e=0..3)
        // and row4col[l*8+e] (e=0..7)
        int c4r0 = col4row[lane * 4 + 0], c4r1 = col4row[lane * 4 + 1];
        int c4r2 = col4row[lane * 4 + 2], c4r3 = col4row[lane * 4 + 3];
        int r4c0 = row4col[lane * 8 + 0], r4c1 = row4col[lane * 8 + 1];
        int r4c2 = row4col[lane * 8 + 2], r4c3 = row4col[lane * 8 + 3];
        int r4c4 = row4col[lane * 8 + 4], r4c5 = row4col[lane * 8 + 5];
        int r4c6 = row4col[lane * 8 + 6], r4c7 = row4col[lane * 8 + 7];

        int tagReg = -1;   // lane-indexed cache tag (slot == lane)
        int rr     = 0;    // wave-uniform round-robin fill pointer

        for (int cur = 0; cur < kNQ; ++cur) {
            // matched-row skip from registers
            {
                const int ce = cur & 3;
                const int t01 = (ce & 1) ? c4r1 : c4r0;
                const int t23 = (ce & 1) ? c4r3 : c4r2;
                const int cv  = (ce & 2) ? t23 : t01;
                if (__builtin_amdgcn_readlane(cv, cur >> 2) >= 0) continue;
            }

            float spcR[8]; int pathR[8]; float mskA[8]; float frzV[8]; int frzP[8]; int frzO[8];
            #pragma unroll
            for (int c = 0; c < 8; ++c) {
                spcR[c] = kInf; pathR[c] = -1; mskA[c] = 0.f;
                frzV[c] = 0.f;  frzP[c] = -1;  frzO[c] = -1;
            }
            unsigned scMask = 0;

            int   i      = cur;
            float minVal = 0.f;
            int   sink   = -1;

            for (int guard = 0; guard < kNT + 2 && sink < 0; ++guard) {
                const float ui = u[i];            // LDS read, overlaps row fetch
                float4 p0, p1;
                const unsigned long long hm = __ballot(tagReg == i);
                if (hm != 0ull) {                 // cache hit (wave-uniform)
                    const int slot = (int)__ffsll(hm) - 1;
                    const float4* lp = (const float4*)&rowCache[slot * kStride + laneOff];
                    p0 = lp[0]; p1 = lp[1];
                } else {                          // miss: global (L2) load
                    const float4* rp = (const float4*)(C + (size_t)i * kNT + lane * 8);
                    p0 = rp[0]; p1 = rp[1];
                    if (guard != 0) {             // don't cache one-shot cur rows
                        float4* wp = (float4*)&rowCache[rr * kStride + laneOff];
                        wp[0] = p0; wp[1] = p1;   // fire-and-forget
                        if (lane == rr) tagReg = i;
                        rr = rr + 1; if (rr == kSlots) rr = 0;
                    }
                }

                // ---- UNMASKED packed relax (value-exact op order) ----
                const v2f cc2[4] = { {p0.x, p0.y}, {p0.z, p0.w},
                                     {p1.x, p1.y}, {p1.z, p1.w} };
                const v2f mv2 = { minVal, minVal };
                const v2f ui2 = { ui, ui };
                float r8[8];
                #pragma unroll
                for (int p = 0; p < 4; ++p) {
                    const v2f vv = { vR[2*p], vR[2*p + 1] };
                    const v2f rp2 = ((mv2 + cc2[p]) - ui2) - vv;
                    r8[2*p] = rp2.x; r8[2*p + 1] = rp2.y;
                }
                #pragma unroll
                for (int c = 0; c < 8; ++c) {
                    const bool lt = r8[c] < spcR[c];
                    spcR[c]  = lt ? r8[c] : spcR[c];
                    pathR[c] = lt ? i : pathR[c];
                }

                // ---- masked local argmin: msk = spc + {0|+inf}, u32 tree ----
                float mskv[8];
                #pragma unroll
                for (int p = 0; p < 4; ++p) {
                    const v2f s2 = { spcR[2*p], spcR[2*p + 1] };
                    const v2f a2 = { mskA[2*p], mskA[2*p + 1] };
                    const v2f m2 = s2 + a2;
                    mskv[2*p] = m2.x; mskv[2*p + 1] = m2.y;
                }
                unsigned sp[8];
                #pragma unroll
                for (int c = 0; c < 8; ++c) sp[c] = __float_as_uint(mskv[c]);
                unsigned mA = sp[1] < sp[0] ? sp[1] : sp[0]; int aA = sp[1] < sp[0] ? 1 : 0;
                unsigned mB = sp[3] < sp[2] ? sp[3] : sp[2]; int aB = sp[3] < sp[2] ? 3 : 2;
                unsigned mC = sp[5] < sp[4] ? sp[5] : sp[4]; int aC = sp[5] < sp[4] ? 5 : 4;
                unsigned mD = sp[7] < sp[6] ? sp[7] : sp[6]; int aD = sp[7] < sp[6] ? 7 : 6;
                unsigned mAB = mB < mA ? mB : mA; int aAB = mB < mA ? aB : aA;
                unsigned mCD = mD < mC ? mD : mC; int aCD = mD < mC ? aD : aC;
                unsigned lvu = mCD < mAB ? mCD : mAB; int lc = mCD < mAB ? aCD : aAB;
                const int lix  = lane * 8 + lc;

                // speculative owner prefetch from REGISTERS (3-level select;
                // independent of the wave_min chain, schedules in parallel)
                const int s01 = (lc & 1) ? r4c1 : r4c0;
                const int s23 = (lc & 1) ? r4c3 : r4c2;
                const int s45 = (lc & 1) ? r4c5 : r4c4;
                const int s67 = (lc & 1) ? r4c7 : r4c6;
                const int sAq = (lc & 2) ? s23 : s01;
                const int sBq = (lc & 2) ? s67 : s45;
                const int spec = (lc & 4) ? sBq : sAq;

                const unsigned gmu = wave_min_u32(lvu);
                const unsigned long long bal = __ballot(lvu == gmu);
                const int wl    = (int)__ffsll(bal) - 1;
                const int jstar = __builtin_amdgcn_readlane(lix, wl);
                const int own   = __builtin_amdgcn_readlane(spec, wl);
                minVal = __uint_as_float(gmu);

                if (own < 0) sink = jstar;
                else         i    = own;

                if (wl == lane) {                 // freeze sweep-time state
                    const int lcw = jstar & 7;
                    scMask |= 1u << lcw;
                    #pragma unroll
                    for (int c = 0; c < 8; ++c) {
                        if (c == lcw) {
                            mskA[c] = __builtin_inff();
                            frzV[c] = minVal;     // == spcR[c] at sweep time
                            frzP[c] = pathR[c];
                            frzO[c] = spec;       // == row4col[jstar] at sweep time
                        }
                    }
                }
            }

            // ---- dual updates (sweep-time values; gathered u reads then
            //      writes — owners distinct by matching invariant) ----
            if (lane == 0) u[cur] += minVal;
            int   rr8[8]; float uv8[8];
            #pragma unroll
            for (int c = 0; c < 8; ++c) rr8[c] = ((scMask >> c) & 1u) ? frzO[c] : -1;
            #pragma unroll
            for (int c = 0; c < 8; ++c) uv8[c] = (rr8[c] >= 0) ? u[rr8[c]] : 0.f;
            #pragma unroll
            for (int c = 0; c < 8; ++c)
                if (rr8[c] >= 0) u[rr8[c]] = uv8[c] + (minVal - frzV[c]);
            #pragma unroll
            for (int c = 0; c < 8; ++c)
                if ((scMask >> c) & 1u) vR[c] -= (minVal - frzV[c]);
            __threadfence_block();

            // ---- augment along alternating path (register-resident;
            //      uniform walk, all lanes participate) ----
            if (sink >= 0) {
                int j = sink;
                while (true) {
                    const int je = j & 7;
                    const int q01 = (je & 1) ? frzP[1] : frzP[0];
                    const int q23 = (je & 1) ? frzP[3] : frzP[2];
                    const int q45 = (je & 1) ? frzP[5] : frzP[4];
                    const int q67 = (je & 1) ? frzP[7] : frzP[6];
                    const int qA  = (je & 2) ? q23 : q01;
                    const int qB  = (je & 2) ? q67 : q45;
                    const int qv  = (je & 4) ? qB : qA;
                    const int pi  = __builtin_amdgcn_readlane(qv, j >> 3);

                    if (lane == (j >> 3)) {       // row4col[j] = pi
                        if (je == 0) r4c0 = pi; if (je == 1) r4c1 = pi;
                        if (je == 2) r4c2 = pi; if (je == 3) r4c3 = pi;
                        if (je == 4) r4c4 = pi; if (je == 5) r4c5 = pi;
                        if (je == 6) r4c6 = pi; if (je == 7) r4c7 = pi;
                    }

                    const int pe  = pi & 3;       // nj = col4row[pi]; col4row[pi] = j
                    const int w01 = (pe & 1) ? c4r1 : c4r0;
                    const int w23 = (pe & 1) ? c4r3 : c4r2;
                    const int wv  = (pe & 2) ? w23 : w01;
                    const int nj  = __builtin_amdgcn_readlane(wv, pi >> 2);
                    if (lane == (pi >> 2)) {
                        if (pe == 0) c4r0 = j; if (pe == 1) c4r1 = j;
                        if (pe == 2) c4r2 = j; if (pe == 3) c4r3 = j;
                    }

                    if (pi == cur) break;
                    j = nj;
                }
            }
        }

        // write matching back to LDS for the output phase
        col4row[lane * 4 + 0] = c4r0; col4row[lane * 4 + 1] = c4r1;
        col4row[lane * 4 + 2] = c4r2; col4row[lane * 4 + 3] = c4r3;
    }
    __syncthreads();

    outInds[(size_t)b * kNQ + tid] = (float)col4row[tid];
    outMask[(size_t)b * kNQ + tid] = 1.0f;
}

extern "C" void kernel_launch(void* const* d_in, const int* in_sizes, int n_in,
                              void* d_out, int out_size, void* d_ws, size_t ws_size,
                              hipStream_t stream) {
    const float* trans = (const float*)d_in[0];
    const float* qpos  = (const float*)d_in[1];
    const float* rot   = (const float*)d_in[2];
    const float* pose  = (const float*)d_in[3];

    float* out  = (float*)d_out;
    float* cost = out;
    float* inds = out + (size_t)kB * kNQ * kNT;
    float* mask = inds + (size_t)kB * kNQ;

    dim3 g1(kB, kNQ / kQTile);
    cost_kernel<<<g1, 512, 0, stream>>>(trans, qpos, rot, pose, cost);
    hungarian_kernel<<<kB, 256, 0, stream>>>(cost, inds, mask);
}

// Round 6
// 429.215 us; speedup vs baseline: 1.1180x; 1.1151x over previous
//
#include <hip/hip_runtime.h>

constexpr int kB  = 32;
constexpr int kNQ = 256;   // rows n
constexpr int kNT = 512;   // cols m
constexpr float kInf = 1e30f;
constexpr int kQTile = 8;     // queries per cost block (grid 1024; measured ~5us better than 32)
constexpr int kSlots = 56;    // LDS row-cache entries
constexpr int kStride = 544;  // 8 groups x (64 data + 4 pad) floats

// ---------------------------------------------------------------------------
// Kernel 1: final_cost [B, NQ, NT]. 512 thr/block, thread == target t.
// Math per output element bit-identical to the proven kernel.
// ---------------------------------------------------------------------------
__global__ __launch_bounds__(512)
void cost_kernel(const float* __restrict__ trans,
                 const float* __restrict__ qpos,
                 const float* __restrict__ rot,
                 const float* __restrict__ pose,
                 float* __restrict__ cost)
{
    __shared__ float sPose[kNT * 23];   // 47104 B -> 3 blocks/CU

    const int b     = blockIdx.x;
    const int qBase = blockIdx.y * kQTile;
    const int tid   = threadIdx.x;      // target index t

    const float* pb = pose + (size_t)b * kNT * 23;
    for (int idx = tid; idx < kNT * 23; idx += 512) sPose[idx] = pb[idx];
    __syncthreads();

    float T[23];
    #pragma unroll
    for (int d = 0; d < 23; ++d) T[d] = sPose[tid * 23 + d];

    float s = 0.f;
    #pragma unroll
    for (int d = 0; d < 23; ++d) s += fabsf(T[d]);
    const bool valid = (s > 0.f);

    const float* tr = trans + ((size_t)b * kNQ + qBase) * 3;
    const float* qp = qpos  + ((size_t)b * kNQ + qBase) * 16;
    const float* rt = rot   + ((size_t)b * kNQ + qBase) * 4;
    float* cb = cost + ((size_t)b * kNQ + qBase) * kNT + tid;

    #pragma unroll
    for (int q = 0; q < kQTile; ++q) {
        const float Q0 = tr[q * 3 + 0], Q1 = tr[q * 3 + 1], Q2 = tr[q * 3 + 2];
        float a = fabsf(Q0 - T[0]);
        a += fabsf(Q1 - T[1]);
        a += fabsf(Q2 - T[2]);
        float bsum = 0.f;
        #pragma unroll
        for (int d = 0; d < 16; ++d) bsum += fabsf(qp[q * 16 + d] - T[3 + d]);
        const float r0 = rt[q * 4 + 0], r1 = rt[q * 4 + 1];
        const float r2 = rt[q * 4 + 2], r3 = rt[q * 4 + 3];
        float dot = r0 * T[19] + r1 * T[20] + r2 * T[21] + r3 * T[22];
        float c = (a + bsum) + (1.0f - fabsf(dot));
        cb[(size_t)q * kNT] = valid ? c : kInf;
    }
}

// Wave64 min-reduction via DPP (rocPRIM pattern). All inputs are non-negative
// float bit-patterns (incl +inf sentinel), so u32 order == f32 order.
__device__ __forceinline__ unsigned wave_min_u32(unsigned x) {
    unsigned t;
    t = (unsigned)__builtin_amdgcn_update_dpp((int)0xFFFFFFFF, (int)x, 0x111, 0xF, 0xF, false); x = t < x ? t : x; // row_shr:1
    t = (unsigned)__builtin_amdgcn_update_dpp((int)0xFFFFFFFF, (int)x, 0x112, 0xF, 0xF, false); x = t < x ? t : x; // row_shr:2
    t = (unsigned)__builtin_amdgcn_update_dpp((int)0xFFFFFFFF, (int)x, 0x114, 0xF, 0xF, false); x = t < x ? t : x; // row_shr:4
    t = (unsigned)__builtin_amdgcn_update_dpp((int)0xFFFFFFFF, (int)x, 0x118, 0xF, 0xF, false); x = t < x ? t : x; // row_shr:8
    t = (unsigned)__builtin_amdgcn_update_dpp((int)0xFFFFFFFF, (int)x, 0x142, 0xF, 0xF, false); x = t < x ? t : x; // row_bcast:15
    t = (unsigned)__builtin_amdgcn_update_dpp((int)0xFFFFFFFF, (int)x, 0x143, 0xF, 0xF, false); x = t < x ? t : x; // row_bcast:31
    return (unsigned)__builtin_amdgcn_readlane((int)x, 63);
}

// ---------------------------------------------------------------------------
// Kernel 2: JV LSAP — EXACT R0 code (proven 353.8us, no outlier dispatches).
// The R1/R2 register-resident-state bundle (reg col4row/row4col, mux spec
// prefetch, reg augment walk, frzO, gathered duals) measured +54us on two
// independent rounds with different cache schemes — attribution confirmed,
// bundle reverted. LDS bookkeeping + lane0 augment walk restored.
// ---------------------------------------------------------------------------
__global__ __launch_bounds__(256)
void hungarian_kernel(const float* __restrict__ cost,
                      float* __restrict__ outInds,
                      float* __restrict__ outMask)
{
    __shared__ float rowCache[kSlots * kStride];  // 121856 B
    __shared__ float u[kNQ];
    __shared__ int   col4row[kNQ];
    __shared__ int   row4col[kNT];
    __shared__ int   colBest[kNT];
    __shared__ int   pathL[kNT];
    __shared__ int   rowArg[kNQ];

    const int b   = blockIdx.x;
    const int tid = threadIdx.x;
    const float* __restrict__ C = cost + (size_t)b * kNQ * kNT;

    // ---- Phase A: row minima + greedy matching (thread t == row t) ----
    {
        const float4* Crow = (const float4*)(C + (size_t)tid * kNT);
        float bm = kInf; int barg = 0;
        #pragma unroll 4
        for (int j4 = 0; j4 < kNT / 4; ++j4) {
            float4 cc = Crow[j4];
            const int jb = j4 * 4;
            if (cc.x < bm) { bm = cc.x; barg = jb + 0; }
            if (cc.y < bm) { bm = cc.y; barg = jb + 1; }
            if (cc.z < bm) { bm = cc.z; barg = jb + 2; }
            if (cc.w < bm) { bm = cc.w; barg = jb + 3; }
        }
        u[tid]      = bm;   // feasible: C - u - 0 >= 0 exactly; matched slack == 0 exactly
        rowArg[tid] = barg;
        col4row[tid] = -1;
    }
    row4col[tid] = -1;         row4col[tid + 256] = -1;
    colBest[tid] = 0x7fffffff; colBest[tid + 256] = 0x7fffffff;
    __syncthreads();
    atomicMin(&colBest[rowArg[tid]], tid);
    __syncthreads();
    {
        const int j = rowArg[tid];
        if (colBest[j] == tid) { col4row[tid] = j; row4col[j] = tid; }
    }
    __syncthreads();

    // ---- Phase C: augmenting searches, wave 0 only (wave-synchronous) ----
    if (tid < 64) {
        const int lane = tid;
        const int laneOff = (lane >> 3) * 68 + (lane & 7) * 8;
        typedef float v2f __attribute__((ext_vector_type(2)));

        float vR[8];
        #pragma unroll
        for (int c = 0; c < 8; ++c) vR[c] = 0.f;

        int tagReg = -1;   // lane-indexed cache tag (slot == lane)
        int rr     = 0;    // wave-uniform round-robin fill pointer

        for (int cur = 0; cur < kNQ; ++cur) {
            if (col4row[cur] >= 0) continue;   // uniform branch

            float spcR[8]; int pathR[8]; float mskA[8]; float frzV[8]; int frzP[8];
            #pragma unroll
            for (int c = 0; c < 8; ++c) {
                spcR[c] = kInf; pathR[c] = -1; mskA[c] = 0.f;
                frzV[c] = 0.f;  frzP[c] = -1;
            }
            unsigned scMask = 0;

            int   i      = cur;
            float minVal = 0.f;
            int   sink   = -1;

            for (int guard = 0; guard < kNT + 2 && sink < 0; ++guard) {
                const float ui = u[i];            // LDS read, overlaps row fetch
                float4 p0, p1;
                const unsigned long long hm = __ballot(tagReg == i);
                if (hm != 0ull) {                 // cache hit (wave-uniform)
                    const int slot = (int)__ffsll(hm) - 1;
                    const float4* lp = (const float4*)&rowCache[slot * kStride + laneOff];
                    p0 = lp[0]; p1 = lp[1];
                } else {                          // miss: global (L2) load
                    const float4* rp = (const float4*)(C + (size_t)i * kNT + lane * 8);
                    p0 = rp[0]; p1 = rp[1];
                    if (guard != 0) {             // don't cache one-shot cur rows
                        float4* wp = (float4*)&rowCache[rr * kStride + laneOff];
                        wp[0] = p0; wp[1] = p1;   // fire-and-forget
                        if (lane == rr) tagReg = i;
                        rr = rr + 1; if (rr == kSlots) rr = 0;
                    }
                }

                // ---- UNMASKED packed relax (value-exact op order) ----
                const v2f cc2[4] = { {p0.x, p0.y}, {p0.z, p0.w},
                                     {p1.x, p1.y}, {p1.z, p1.w} };
                const v2f mv2 = { minVal, minVal };
                const v2f ui2 = { ui, ui };
                float r8[8];
                #pragma unroll
                for (int p = 0; p < 4; ++p) {
                    const v2f vv = { vR[2*p], vR[2*p + 1] };
                    const v2f rp2 = ((mv2 + cc2[p]) - ui2) - vv;
                    r8[2*p] = rp2.x; r8[2*p + 1] = rp2.y;
                }
                #pragma unroll
                for (int c = 0; c < 8; ++c) {
                    const bool lt = r8[c] < spcR[c];
                    spcR[c]  = lt ? r8[c] : spcR[c];
                    pathR[c] = lt ? i : pathR[c];
                }

                // ---- masked local argmin: msk = spc + {0|+inf}, u32 tree ----
                float mskv[8];
                #pragma unroll
                for (int p = 0; p < 4; ++p) {
                    const v2f s2 = { spcR[2*p], spcR[2*p + 1] };
                    const v2f a2 = { mskA[2*p], mskA[2*p + 1] };
                    const v2f m2 = s2 + a2;
                    mskv[2*p] = m2.x; mskv[2*p + 1] = m2.y;
                }
                unsigned sp[8];
                #pragma unroll
                for (int c = 0; c < 8; ++c) sp[c] = __float_as_uint(mskv[c]);
                unsigned mA = sp[1] < sp[0] ? sp[1] : sp[0]; int aA = sp[1] < sp[0] ? 1 : 0;
                unsigned mB = sp[3] < sp[2] ? sp[3] : sp[2]; int aB = sp[3] < sp[2] ? 3 : 2;
                unsigned mC = sp[5] < sp[4] ? sp[5] : sp[4]; int aC = sp[5] < sp[4] ? 5 : 4;
                unsigned mD = sp[7] < sp[6] ? sp[7] : sp[6]; int aD = sp[7] < sp[6] ? 7 : 6;
                unsigned mAB = mB < mA ? mB : mA; int aAB = mB < mA ? aB : aA;
                unsigned mCD = mD < mC ? mD : mC; int aCD = mD < mC ? aD : aC;
                unsigned lvu = mCD < mAB ? mCD : mAB; int lc = mCD < mAB ? aCD : aAB;
                const int lix  = lane * 8 + lc;
                const int spec = row4col[lix];          // speculative owner prefetch

                const unsigned gmu = wave_min_u32(lvu); // hides the LDS read above
                const unsigned long long bal = __ballot(lvu == gmu);
                const int wl    = (int)__ffsll(bal) - 1;
                const int jstar = __builtin_amdgcn_readlane(lix, wl);
                const int own   = __builtin_amdgcn_readlane(spec, wl);
                minVal = __uint_as_float(gmu);

                if (own < 0) sink = jstar;
                else         i    = own;

                if (wl == lane) {                 // freeze sweep-time state
                    const int lcw = jstar & 7;
                    scMask |= 1u << lcw;
                    #pragma unroll
                    for (int c = 0; c < 8; ++c) {
                        if (c == lcw) {
                            mskA[c] = __builtin_inff();
                            frzV[c] = minVal;     // == spcR[c] at sweep time
                            frzP[c] = pathR[c];
                        }
                    }
                }
            }

            // ---- dual updates (sweep-time values, per swept column) ----
            if (lane == 0) u[cur] += minVal;
            #pragma unroll
            for (int c = 0; c < 8; ++c) {
                if ((scMask >> c) & 1u) {
                    const int j = lane * 8 + c;
                    const int r = row4col[j];
                    const float d = minVal - frzV[c];
                    if (r >= 0) u[r] += d;   // owners distinct (matching invariant)
                    vR[c] -= d;
                    pathL[j] = frzP[c];
                }
            }
            __threadfence_block();

            // ---- augment along alternating path (lane 0) ----
            if (lane == 0 && sink >= 0) {
                int j = sink;
                while (true) {
                    const int pi = pathL[j];
                    row4col[j] = pi;
                    const int nj = col4row[pi];
                    col4row[pi] = j;
                    if (pi == cur) break;
                    j = nj;
                }
            }
            __threadfence_block();
        }
    }
    __syncthreads();

    outInds[(size_t)b * kNQ + tid] = (float)col4row[tid];
    outMask[(size_t)b * kNQ + tid] = 1.0f;
}

extern "C" void kernel_launch(void* const* d_in, const int* in_sizes, int n_in,
                              void* d_out, int out_size, void* d_ws, size_t ws_size,
                              hipStream_t stream) {
    const float* trans = (const float*)d_in[0];
    const float* qpos  = (const float*)d_in[1];
    const float* rot   = (const float*)d_in[2];
    const float* pose  = (const float*)d_in[3];

    float* out  = (float*)d_out;
    float* cost = out;
    float* inds = out + (size_t)kB * kNQ * kNT;
    float* mask = inds + (size_t)kB * kNQ;

    dim3 g1(kB, kNQ / kQTile);
    cost_kernel<<<g1, 512, 0, stream>>>(trans, qpos, rot, pose, cost);
    hungarian_kernel<<<kB, 256, 0, stream>>>(cost, inds, mask);
}